// Round 4
// baseline (577.690 us; speedup 1.0000x reference)
//
#include <hip/hip_runtime.h>
#include <hip/hip_bf16.h>
#include <math.h>

#define BB 64
#define TT 8192
#define DD 128
#define NC 8          // t-chunks for z partial reduction
#define TCH (TT / NC) // 1024

// ---------------------------------------------------------------------------
// Kernel 1: fkp[b,o] = dot(Wa_w[o,:], h_tm1[b,:]) + Wa_b[o]
// ---------------------------------------------------------------------------
__global__ __launch_bounds__(DD) void fkprime_kernel(
    const float* __restrict__ Waw, const float* __restrict__ Wab,
    const float* __restrict__ h_tm1, float* __restrict__ fkp) {
    const int b = blockIdx.x;
    const int o = threadIdx.x;
    const float* __restrict__ w = Waw + o * DD;
    const float* __restrict__ h = h_tm1 + b * DD;
    float a0 = 0.f, a1 = 0.f, a2 = 0.f, a3 = 0.f;
#pragma unroll
    for (int d = 0; d < DD; d += 4) {
        float4 w4 = *reinterpret_cast<const float4*>(w + d);
        a0 = fmaf(w4.x, h[d + 0], a0);
        a1 = fmaf(w4.y, h[d + 1], a1);
        a2 = fmaf(w4.z, h[d + 2], a2);
        a3 = fmaf(w4.w, h[d + 3], a3);
    }
    fkp[b * DD + o] = (a0 + a1) + (a2 + a3) + Wab[o];
}

// ---------------------------------------------------------------------------
// Kernel 2: beta_raw[b,t] = c + sum_o tanh(H[b,t,:].V_w[o,:] + V_b[o] + fkp[b,o])*v[o]
// One thread per (b,t); H row in 128 VGPRs; V_w rows wave-uniform -> s_loads.
// ---------------------------------------------------------------------------
__global__ __launch_bounds__(256) void beta_kernel(
    const float* __restrict__ H, const float* __restrict__ Vw,
    const float* __restrict__ Vb, const float* __restrict__ fkp,
    const float* __restrict__ vvec, const float* __restrict__ cptr,
    float* __restrict__ beta_raw) {
    const int g = blockIdx.x * 256 + threadIdx.x; // 0 .. B*T-1
    const int b = g >> 13;                        // T = 8192 = 2^13
    const float* __restrict__ Hrow = H + (size_t)g * DD;

    float h[DD];
#pragma unroll
    for (int d = 0; d < DD; d += 4) {
        float4 t4 = *reinterpret_cast<const float4*>(Hrow + d);
        h[d + 0] = t4.x; h[d + 1] = t4.y; h[d + 2] = t4.z; h[d + 3] = t4.w;
    }

    const float* __restrict__ p = fkp + b * DD;
    float r = cptr[0];
    for (int o = 0; o < DD; ++o) {
        const float* __restrict__ Vrow = Vw + o * DD;
        float a0 = 0.f, a1 = 0.f, a2 = 0.f, a3 = 0.f;
#pragma unroll
        for (int d = 0; d < DD; d += 4) {
            float4 w4 = *reinterpret_cast<const float4*>(Vrow + d);
            a0 = fmaf(h[d + 0], w4.x, a0);
            a1 = fmaf(h[d + 1], w4.y, a1);
            a2 = fmaf(h[d + 2], w4.z, a2);
            a3 = fmaf(h[d + 3], w4.w, a3);
        }
        float dot = (a0 + a1) + (a2 + a3);
        r = fmaf(tanhf(dot + Vb[o] + p[o]), vvec[o], r);
    }
    beta_raw[g] = r;
}

// ---------------------------------------------------------------------------
// Kernel 3: masked softmax (literal reference order), writes f32 beta to d_out.
// ---------------------------------------------------------------------------
__global__ __launch_bounds__(256) void softmax_kernel(
    const float* __restrict__ beta_raw, const int* __restrict__ mask,
    float* __restrict__ out_beta) {
    const int b = blockIdx.x;
    const int tid = threadIdx.x;
    const float* __restrict__ x = beta_raw + (size_t)b * TT;
    const int* __restrict__ mrow = mask + (size_t)b * TT;
    __shared__ float s_red[256];

    // max over clip(x)*m (masked zeros participate, as in the reference)
    float lmax = -1e30f;
    for (int t = tid; t < TT; t += 256) {
        float xv = fminf(fmaxf(x[t], -15.f), 15.f);
        lmax = fmaxf(lmax, xv * (float)mrow[t]);
    }
    s_red[tid] = lmax;
    __syncthreads();
    for (int s = 128; s > 0; s >>= 1) {
        if (tid < s) s_red[tid] = fmaxf(s_red[tid], s_red[tid + s]);
        __syncthreads();
    }
    const float gmax = s_red[0];
    __syncthreads();

    float lsum = 0.f;
    for (int t = tid; t < TT; t += 256) {
        float xv = fminf(fmaxf(x[t], -15.f), 15.f);
        float mv = (float)mrow[t];
        lsum += expf(xv * mv - gmax) * mv;
    }
    s_red[tid] = lsum;
    __syncthreads();
    for (int s = 128; s > 0; s >>= 1) {
        if (tid < s) s_red[tid] += s_red[tid + s];
        __syncthreads();
    }
    const float denom = s_red[0] + 1e-6f;
    __syncthreads();

    for (int t = tid; t < TT; t += 256) {
        float xv = fminf(fmaxf(x[t], -15.f), 15.f);
        float mv = (float)mrow[t];
        float e = expf(xv * mv - gmax) * mv;
        out_beta[(size_t)b * TT + t] = e / denom;
    }
}

// ---------------------------------------------------------------------------
// Kernel 4: zpart[b,c,d] = sum_{t in chunk c} beta[b,t]*H[b,t,d]
// ---------------------------------------------------------------------------
__global__ __launch_bounds__(256) void zpart_kernel(
    const float* __restrict__ H, const float* __restrict__ beta,
    float* __restrict__ zpart) {
    const int b = blockIdx.x, cch = blockIdx.y;
    const int tid = threadIdx.x;
    const int d0 = (tid & 31) * 4; // 32 lanes x float4 cover 128 d
    const int tg = tid >> 5;       // 8 t-groups
    const float* __restrict__ Hb = H + ((size_t)b * TT + (size_t)cch * TCH) * DD;
    const float* __restrict__ bb = beta + (size_t)b * TT + (size_t)cch * TCH;

    float4 acc = make_float4(0.f, 0.f, 0.f, 0.f);
    for (int t = tg; t < TCH; t += 8) {
        float w = bb[t];
        float4 h4 = *reinterpret_cast<const float4*>(Hb + (size_t)t * DD + d0);
        acc.x = fmaf(w, h4.x, acc.x);
        acc.y = fmaf(w, h4.y, acc.y);
        acc.z = fmaf(w, h4.z, acc.z);
        acc.w = fmaf(w, h4.w, acc.w);
    }
    __shared__ float4 red[8][32];
    red[tg][tid & 31] = acc;
    __syncthreads();
    if (tid < 32) {
        float4 s = red[0][tid];
#pragma unroll
        for (int g2 = 1; g2 < 8; ++g2) {
            float4 r2 = red[g2][tid];
            s.x += r2.x; s.y += r2.y; s.z += r2.z; s.w += r2.w;
        }
        *reinterpret_cast<float4*>(zpart + ((size_t)b * NC + cch) * DD + tid * 4) = s;
    }
}

// ---------------------------------------------------------------------------
// Kernel 5: z[b,d] = sum_c zpart[b,c,d] -> f32 output
// ---------------------------------------------------------------------------
__global__ __launch_bounds__(256) void zfinal_kernel(
    const float* __restrict__ zpart, float* __restrict__ out_z) {
    const int idx = blockIdx.x * 256 + threadIdx.x; // 0 .. B*D-1
    const int b = idx >> 7, d = idx & 127;
    float s = 0.f;
#pragma unroll
    for (int cc = 0; cc < NC; ++cc) s += zpart[((size_t)b * NC + cc) * DD + d];
    out_z[idx] = s;
}

// ---------------------------------------------------------------------------
extern "C" void kernel_launch(void* const* d_in, const int* in_sizes, int n_in,
                              void* d_out, int out_size, void* d_ws, size_t ws_size,
                              hipStream_t stream) {
    const float* H     = (const float*)d_in[0]; // [B,T,D] f32
    const int*   mask  = (const int*)d_in[1];   // [B,T] int32
    const float* h_tm1 = (const float*)d_in[2]; // [B,D] f32
    const float* V_w   = (const float*)d_in[3]; // [D,D] f32
    const float* V_b   = (const float*)d_in[4]; // [D] f32
    const float* Wa_w  = (const float*)d_in[5]; // [D,D] f32
    const float* Wa_b  = (const float*)d_in[6]; // [D] f32
    const float* v     = (const float*)d_in[7]; // [D] f32
    const float* c     = (const float*)d_in[8]; // [1] f32

    // OUTPUTS ARE FLOAT32 (reference returns f32; bf16 label is only the
    // comparison tolerance mode). (z, beta) concatenated.
    float* out_z    = (float*)d_out;           // B*D
    float* out_beta = (float*)d_out + BB * DD; // B*T

    float* ws       = (float*)d_ws;
    float* fkp      = ws;               // B*D    = 8192 f32
    float* beta_raw = ws + BB * DD;     // B*T    = 524288 f32
    float* zpart    = beta_raw + BB * TT; // B*NC*D = 65536 f32

    fkprime_kernel<<<BB, DD, 0, stream>>>(Wa_w, Wa_b, h_tm1, fkp);
    beta_kernel<<<(BB * TT) / 256, 256, 0, stream>>>(H, V_w, V_b, fkp, v, c, beta_raw);
    softmax_kernel<<<BB, 256, 0, stream>>>(beta_raw, mask, out_beta);
    zpart_kernel<<<dim3(BB, NC), 256, 0, stream>>>(H, out_beta, zpart);
    zfinal_kernel<<<(BB * DD) / 256, 256, 0, stream>>>(zpart, out_z);
}

// Round 6
// 259.005 us; speedup vs baseline: 2.2304x; 2.2304x over previous
//
#include <hip/hip_runtime.h>
#include <math.h>

#define BB 64
#define TT 8192
#define DD 128
#define NC 8          // t-chunks for z partial reduction
#define TCH (TT / NC) // 1024

typedef float f32x4 __attribute__((ext_vector_type(4)));
typedef __bf16 bf16x8 __attribute__((ext_vector_type(8)));

// ---------------------------------------------------------------------------
// Kernel 0: V_w f32 -> bf16 (32 KB, stays L2-resident for the GEMM)
// ---------------------------------------------------------------------------
__global__ __launch_bounds__(256) void convw_kernel(const float* __restrict__ Vw,
                                                    __bf16* __restrict__ Vw_bf) {
    const int i = blockIdx.x * 256 + threadIdx.x; // DD*DD = 16384 total
    Vw_bf[i] = (__bf16)Vw[i];
}

// ---------------------------------------------------------------------------
// Kernel 1: fkp[b,o] = dot(Wa_w[o,:], h_tm1[b,:]) + Wa_b[o]
// ---------------------------------------------------------------------------
__global__ __launch_bounds__(DD) void fkprime_kernel(
    const float* __restrict__ Waw, const float* __restrict__ Wab,
    const float* __restrict__ h_tm1, float* __restrict__ fkp) {
    const int b = blockIdx.x;
    const int o = threadIdx.x;
    const float* __restrict__ w = Waw + o * DD;
    const float* __restrict__ h = h_tm1 + b * DD;
    float a0 = 0.f, a1 = 0.f, a2 = 0.f, a3 = 0.f;
#pragma unroll
    for (int d = 0; d < DD; d += 4) {
        float4 w4 = *reinterpret_cast<const float4*>(w + d);
        a0 = fmaf(w4.x, h[d + 0], a0);
        a1 = fmaf(w4.y, h[d + 1], a1);
        a2 = fmaf(w4.z, h[d + 2], a2);
        a3 = fmaf(w4.w, h[d + 3], a3);
    }
    fkp[b * DD + o] = (a0 + a1) + (a2 + a3) + Wab[o];
}

// ---------------------------------------------------------------------------
// Kernel 2 (MFMA): S = H @ V_w^T via 16x16x32 bf16 MFMA, fused epilogue
//   beta_raw[g] = c + sum_o tanh(S[g,o] + Vb[o] + fkp[b,o]) * v[o]
// Block = 256 thr = 4 waves; block tile = 64 rows; wave tile = 16 rows x 128.
// A and B fragments use the SAME (lane,elem)->k formula (k = (lane>>4)*8+j,
// 8 contiguous elems of row lane&15) -> correct regardless of the HW k-slot
// convention (dot is k-permutation-invariant). C/D: col=lane&15,
// row=(lane>>4)*4+j (HW-verified mapping).
// ---------------------------------------------------------------------------
__global__ __launch_bounds__(256) void beta_mfma_kernel(
    const float* __restrict__ H, const __bf16* __restrict__ Vw_bf,
    const float* __restrict__ Vb, const float* __restrict__ fkp,
    const float* __restrict__ vvec, const float* __restrict__ cptr,
    float* __restrict__ beta_raw) {
    const int tid  = threadIdx.x;
    const int wv   = tid >> 6;
    const int lane = tid & 63;
    const int row0 = blockIdx.x * 64;  // 64 | T, so whole block is one b
    const int rw   = row0 + wv * 16;
    const int b    = row0 >> 13;       // T = 8192
    const int cl   = lane & 15;        // row-in-tile (A) / col-in-tile (B,D)
    const int kg   = lane >> 4;        // k-group

    f32x4 acc[8];
#pragma unroll
    for (int nt = 0; nt < 8; ++nt) acc[nt] = (f32x4){0.f, 0.f, 0.f, 0.f};

    const float* __restrict__ Arow = H + (size_t)(rw + cl) * DD + kg * 8;
#pragma unroll
    for (int kk = 0; kk < 4; ++kk) {
        float4 a0 = *reinterpret_cast<const float4*>(Arow + kk * 32);
        float4 a1 = *reinterpret_cast<const float4*>(Arow + kk * 32 + 4);
        bf16x8 af;
        af[0] = (__bf16)a0.x; af[1] = (__bf16)a0.y;
        af[2] = (__bf16)a0.z; af[3] = (__bf16)a0.w;
        af[4] = (__bf16)a1.x; af[5] = (__bf16)a1.y;
        af[6] = (__bf16)a1.z; af[7] = (__bf16)a1.w;
#pragma unroll
        for (int nt = 0; nt < 8; ++nt) {
            bf16x8 bfr = *reinterpret_cast<const bf16x8*>(
                Vw_bf + (size_t)(nt * 16 + cl) * DD + kk * 32 + kg * 8);
            acc[nt] = __builtin_amdgcn_mfma_f32_16x16x32_bf16(af, bfr, acc[nt], 0, 0, 0);
        }
    }

    // epilogue: tanh + v-weighted row sum. Lane holds rows rw+kg*4+j at col
    // nt*16+cl -> local sum over nt, then 16-lane butterfly over cl.
    float part[4] = {0.f, 0.f, 0.f, 0.f};
#pragma unroll
    for (int nt = 0; nt < 8; ++nt) {
        const int col = nt * 16 + cl;
        const float bias = Vb[col] + fkp[b * DD + col];
        const float vv = vvec[col];
#pragma unroll
        for (int j = 0; j < 4; ++j)
            part[j] = fmaf(tanhf(acc[nt][j] + bias), vv, part[j]);
    }
#pragma unroll
    for (int off = 1; off < 16; off <<= 1) {
#pragma unroll
        for (int j = 0; j < 4; ++j) part[j] += __shfl_xor(part[j], off);
    }
    if (cl == 0) {
        const float cval = cptr[0];
#pragma unroll
        for (int j = 0; j < 4; ++j)
            beta_raw[rw + kg * 4 + j] = cval + part[j];
    }
}

// ---------------------------------------------------------------------------
// Kernel 3: masked softmax (literal reference order), writes f32 beta to d_out.
// ---------------------------------------------------------------------------
__global__ __launch_bounds__(256) void softmax_kernel(
    const float* __restrict__ beta_raw, const int* __restrict__ mask,
    float* __restrict__ out_beta) {
    const int b = blockIdx.x;
    const int tid = threadIdx.x;
    const float* __restrict__ x = beta_raw + (size_t)b * TT;
    const int* __restrict__ mrow = mask + (size_t)b * TT;
    __shared__ float s_red[256];

    float lmax = -1e30f;
    for (int t = tid; t < TT; t += 256) {
        float xv = fminf(fmaxf(x[t], -15.f), 15.f);
        lmax = fmaxf(lmax, xv * (float)mrow[t]);
    }
    s_red[tid] = lmax;
    __syncthreads();
    for (int s = 128; s > 0; s >>= 1) {
        if (tid < s) s_red[tid] = fmaxf(s_red[tid], s_red[tid + s]);
        __syncthreads();
    }
    const float gmax = s_red[0];
    __syncthreads();

    float lsum = 0.f;
    for (int t = tid; t < TT; t += 256) {
        float xv = fminf(fmaxf(x[t], -15.f), 15.f);
        float mv = (float)mrow[t];
        lsum += expf(xv * mv - gmax) * mv;
    }
    s_red[tid] = lsum;
    __syncthreads();
    for (int s = 128; s > 0; s >>= 1) {
        if (tid < s) s_red[tid] += s_red[tid + s];
        __syncthreads();
    }
    const float denom = s_red[0] + 1e-6f;
    __syncthreads();

    for (int t = tid; t < TT; t += 256) {
        float xv = fminf(fmaxf(x[t], -15.f), 15.f);
        float mv = (float)mrow[t];
        float e = expf(xv * mv - gmax) * mv;
        out_beta[(size_t)b * TT + t] = e / denom;
    }
}

// ---------------------------------------------------------------------------
// Kernel 4: zpart[b,c,d] = sum_{t in chunk c} beta[b,t]*H[b,t,d]
// ---------------------------------------------------------------------------
__global__ __launch_bounds__(256) void zpart_kernel(
    const float* __restrict__ H, const float* __restrict__ beta,
    float* __restrict__ zpart) {
    const int b = blockIdx.x, cch = blockIdx.y;
    const int tid = threadIdx.x;
    const int d0 = (tid & 31) * 4;
    const int tg = tid >> 5;
    const float* __restrict__ Hb = H + ((size_t)b * TT + (size_t)cch * TCH) * DD;
    const float* __restrict__ bb = beta + (size_t)b * TT + (size_t)cch * TCH;

    float4 acc = make_float4(0.f, 0.f, 0.f, 0.f);
    for (int t = tg; t < TCH; t += 8) {
        float w = bb[t];
        float4 h4 = *reinterpret_cast<const float4*>(Hb + (size_t)t * DD + d0);
        acc.x = fmaf(w, h4.x, acc.x);
        acc.y = fmaf(w, h4.y, acc.y);
        acc.z = fmaf(w, h4.z, acc.z);
        acc.w = fmaf(w, h4.w, acc.w);
    }
    __shared__ float4 red[8][32];
    red[tg][tid & 31] = acc;
    __syncthreads();
    if (tid < 32) {
        float4 s = red[0][tid];
#pragma unroll
        for (int g2 = 1; g2 < 8; ++g2) {
            float4 r2 = red[g2][tid];
            s.x += r2.x; s.y += r2.y; s.z += r2.z; s.w += r2.w;
        }
        *reinterpret_cast<float4*>(zpart + ((size_t)b * NC + cch) * DD + tid * 4) = s;
    }
}

// ---------------------------------------------------------------------------
// Kernel 5: z[b,d] = sum_c zpart[b,c,d] -> f32 output
// ---------------------------------------------------------------------------
__global__ __launch_bounds__(256) void zfinal_kernel(
    const float* __restrict__ zpart, float* __restrict__ out_z) {
    const int idx = blockIdx.x * 256 + threadIdx.x; // 0 .. B*D-1
    const int b = idx >> 7, d = idx & 127;
    float s = 0.f;
#pragma unroll
    for (int cc = 0; cc < NC; ++cc) s += zpart[((size_t)b * NC + cc) * DD + d];
    out_z[idx] = s;
}

// ---------------------------------------------------------------------------
extern "C" void kernel_launch(void* const* d_in, const int* in_sizes, int n_in,
                              void* d_out, int out_size, void* d_ws, size_t ws_size,
                              hipStream_t stream) {
    const float* H     = (const float*)d_in[0]; // [B,T,D] f32
    const int*   mask  = (const int*)d_in[1];   // [B,T] int32
    const float* h_tm1 = (const float*)d_in[2]; // [B,D] f32
    const float* V_w   = (const float*)d_in[3]; // [D,D] f32
    const float* V_b   = (const float*)d_in[4]; // [D] f32
    const float* Wa_w  = (const float*)d_in[5]; // [D,D] f32
    const float* Wa_b  = (const float*)d_in[6]; // [D] f32
    const float* v     = (const float*)d_in[7]; // [D] f32
    const float* c     = (const float*)d_in[8]; // [1] f32

    float* out_z    = (float*)d_out;           // B*D f32
    float* out_beta = (float*)d_out + BB * DD; // B*T f32

    float* ws       = (float*)d_ws;
    float* fkp      = ws;                   // B*D    = 8192 f32
    float* beta_raw = fkp + BB * DD;        // B*T    = 524288 f32
    float* zpart    = beta_raw + BB * TT;   // B*NC*D = 65536 f32
    __bf16* Vw_bf   = (__bf16*)(zpart + BB * NC * DD); // D*D bf16

    convw_kernel<<<(DD * DD) / 256, 256, 0, stream>>>(V_w, Vw_bf);
    fkprime_kernel<<<BB, DD, 0, stream>>>(Wa_w, Wa_b, h_tm1, fkp);
    beta_mfma_kernel<<<(BB * TT) / 64, 256, 0, stream>>>(H, Vw_bf, V_b, fkp, v, c, beta_raw);
    softmax_kernel<<<BB, 256, 0, stream>>>(beta_raw, mask, out_beta);
    zpart_kernel<<<dim3(BB, NC), 256, 0, stream>>>(H, out_beta, zpart);
    zfinal_kernel<<<(BB * DD) / 256, 256, 0, stream>>>(zpart, out_z);
}

// Round 7
// 177.435 us; speedup vs baseline: 3.2558x; 1.4597x over previous
//
#include <hip/hip_runtime.h>
#include <math.h>

#define BB 64
#define TT 8192
#define DD 128
#define RPB 128                 // rows per block
#define BPB (TT / RPB)          // blocks per batch row = 64
#define NBLK (BB * TT / RPB)    // 4096

typedef float f32x4 __attribute__((ext_vector_type(4)));
typedef __bf16 bf16x8 __attribute__((ext_vector_type(8)));

__device__ __forceinline__ float fast_tanh(float x) {
    // tanh(x) = 1 - 2/(e^{2x}+1); x bounded ~±20 here -> no overflow issues
    float t = __expf(2.f * x);
    return 1.f - 2.f * __builtin_amdgcn_rcpf(t + 1.f);
}

__device__ __forceinline__ bf16x8 cvt8(float4 a, float4 b) {
    bf16x8 r;
    r[0] = (__bf16)a.x; r[1] = (__bf16)a.y; r[2] = (__bf16)a.z; r[3] = (__bf16)a.w;
    r[4] = (__bf16)b.x; r[5] = (__bf16)b.y; r[6] = (__bf16)b.z; r[7] = (__bf16)b.w;
    return r;
}

// ---------------------------------------------------------------------------
// Kernel 1: fkp[b,o] = dot(Wa_w[o,:], h_tm1[b,:]) + Wa_b[o]
// ---------------------------------------------------------------------------
__global__ __launch_bounds__(DD) void fkprime_kernel(
    const float* __restrict__ Waw, const float* __restrict__ Wab,
    const float* __restrict__ h_tm1, float* __restrict__ fkp) {
    const int b = blockIdx.x;
    const int o = threadIdx.x;
    const float* __restrict__ w = Waw + o * DD;
    const float* __restrict__ h = h_tm1 + b * DD;
    float a0 = 0.f, a1 = 0.f, a2 = 0.f, a3 = 0.f;
#pragma unroll
    for (int d = 0; d < DD; d += 4) {
        float4 w4 = *reinterpret_cast<const float4*>(w + d);
        a0 = fmaf(w4.x, h[d + 0], a0);
        a1 = fmaf(w4.y, h[d + 1], a1);
        a2 = fmaf(w4.z, h[d + 2], a2);
        a3 = fmaf(w4.w, h[d + 3], a3);
    }
    fkp[b * DD + o] = (a0 + a1) + (a2 + a3) + Wab[o];
}

// ---------------------------------------------------------------------------
// Kernel 2: fused scores + e' + z-partials. One block = 128 rows of one b.
//  - V_w staged f32->bf16 in LDS (XOR swizzle byte^=((row&7)<<4), conflict-free
//    b128 phases), MFMA 16x16x32, 2 row-tiles per wave (64 MFMA/thread).
//  - epilogue: s = c + sum_o tanh(S+Vb+fkp)*v ; x = clip(s)*m ;
//    e' = exp(x-15)*m  (exact softmax numerator scaled by e^{gmax-15})
//  - z-partial: zpart[blk][d] = sum_{t in blk} e'_t * H[t,d]  (H is L2-hot)
// ---------------------------------------------------------------------------
__global__ __launch_bounds__(256, 4) void beta_z_kernel(
    const float* __restrict__ H, const float* __restrict__ Vw,
    const float* __restrict__ Vb, const float* __restrict__ fkp,
    const float* __restrict__ vvec, const float* __restrict__ cptr,
    const int* __restrict__ mask,
    float* __restrict__ eout,      // d_out beta region (e' before normalize)
    float* __restrict__ zpart) {   // [NBLK][DD]
    const int tid  = threadIdx.x;
    const int wv   = tid >> 6;
    const int lane = tid & 63;
    const int cl   = lane & 15;
    const int kg   = lane >> 4;
    const int row0 = blockIdx.x * RPB;
    const int b    = row0 >> 13; // T = 8192

    __shared__ short s_vw[DD * DD];   // 32 KB swizzled bf16 V_w
    __shared__ float s_ep[RPB];       // e' per row
    __shared__ float s_z[2][DD];

    // ---- stage V_w into LDS (f32 -> bf16), XOR-swizzled ----
    {
        const int r = tid >> 1, hf = tid & 1;
        const float* __restrict__ src = Vw + r * DD + hf * 64;
        char* base = (char*)s_vw + r * 256;
#pragma unroll
        for (int j = 0; j < 8; ++j) {
            float4 x0 = *reinterpret_cast<const float4*>(src + j * 8);
            float4 x1 = *reinterpret_cast<const float4*>(src + j * 8 + 4);
            const int cb = (hf * 8 + j) * 16;
            *reinterpret_cast<bf16x8*>(base + (cb ^ ((r & 7) << 4))) = cvt8(x0, x1);
        }
    }
    __syncthreads();

    // ---- GEMM: 2 row-tiles (32 rows) per wave x 128 cols ----
    const int rA0 = row0 + wv * 32;
    f32x4 acc[2][8];
#pragma unroll
    for (int T = 0; T < 2; ++T)
#pragma unroll
        for (int nt = 0; nt < 8; ++nt) acc[T][nt] = (f32x4){0.f, 0.f, 0.f, 0.f};

    const float* __restrict__ A0 = H + (size_t)(rA0 + cl) * DD + kg * 8;
    const float* __restrict__ A1 = A0 + 16 * DD;
#pragma unroll
    for (int kk = 0; kk < 4; ++kk) {
        bf16x8 af0 = cvt8(*reinterpret_cast<const float4*>(A0 + kk * 32),
                          *reinterpret_cast<const float4*>(A0 + kk * 32 + 4));
        bf16x8 af1 = cvt8(*reinterpret_cast<const float4*>(A1 + kk * 32),
                          *reinterpret_cast<const float4*>(A1 + kk * 32 + 4));
#pragma unroll
        for (int nt = 0; nt < 8; ++nt) {
            const int row = nt * 16 + cl;
            const int cb = (kk * 64 + kg * 16) ^ ((row & 7) << 4);
            bf16x8 bfr = *reinterpret_cast<const bf16x8*>((const char*)s_vw + row * 256 + cb);
            acc[0][nt] = __builtin_amdgcn_mfma_f32_16x16x32_bf16(af0, bfr, acc[0][nt], 0, 0, 0);
            acc[1][nt] = __builtin_amdgcn_mfma_f32_16x16x32_bf16(af1, bfr, acc[1][nt], 0, 0, 0);
        }
    }

    // ---- epilogue: tanh, v-weighted row-sum, e' ----
    const float cval = cptr[0];
#pragma unroll
    for (int T = 0; T < 2; ++T) {
        float part[4] = {0.f, 0.f, 0.f, 0.f};
#pragma unroll
        for (int nt = 0; nt < 8; ++nt) {
            const int col = nt * 16 + cl;
            const float bias = Vb[col] + fkp[b * DD + col];
            const float vvl  = vvec[col];
#pragma unroll
            for (int j = 0; j < 4; ++j)
                part[j] = fmaf(fast_tanh(acc[T][nt][j] + bias), vvl, part[j]);
        }
#pragma unroll
        for (int off = 1; off < 16; off <<= 1) {
#pragma unroll
            for (int j = 0; j < 4; ++j) part[j] += __shfl_xor(part[j], off);
        }
        if (cl == 0) {
#pragma unroll
            for (int j = 0; j < 4; ++j) {
                const int g = rA0 + T * 16 + kg * 4 + j; // global row (= b*T+t)
                float x  = fminf(fmaxf(cval + part[j], -15.f), 15.f);
                float mv = (float)mask[g];
                float ep = __expf(x * mv - 15.f) * mv;
                eout[g] = ep;
                s_ep[g - row0] = ep;
            }
        }
    }
    __syncthreads();

    // ---- z-partial over this block's 128 rows (H tile is L2-hot) ----
    const int d   = tid & 127;
    const int hf2 = tid >> 7;
    const float* __restrict__ Hb = H + (size_t)row0 * DD;
    float a = 0.f;
    for (int t = hf2; t < RPB; t += 2)
        a = fmaf(s_ep[t], Hb[(size_t)t * DD + d], a);
    s_z[hf2][d] = a;
    __syncthreads();
    if (tid < DD)
        zpart[(size_t)blockIdx.x * DD + tid] = s_z[0][tid] + s_z[1][tid];
}

// ---------------------------------------------------------------------------
// Kernel 3: per-b denom = sum(e') + 1e-6 * e^{gmax-15}; normalize beta in place.
// e^{gmax-15} = any_masked ? max(max e', e^-15) : max e'   (exact ref semantics)
// ---------------------------------------------------------------------------
__global__ __launch_bounds__(256) void denom_kernel(
    float* __restrict__ eout, const int* __restrict__ mask,
    float* __restrict__ denom) {
    const int b = blockIdx.x, tid = threadIdx.x;
    float* __restrict__ e = eout + (size_t)b * TT;
    const int* __restrict__ mrow = mask + (size_t)b * TT;
    __shared__ float sE[256], sM[256];
    __shared__ int sA[256];

    float E = 0.f, M = 0.f;
    int any0 = 0;
    for (int t = tid; t < TT; t += 256) {
        float ep = e[t];
        E += ep;
        M = fmaxf(M, ep);
        any0 |= (mrow[t] == 0);
    }
    sE[tid] = E; sM[tid] = M; sA[tid] = any0;
    __syncthreads();
    for (int s = 128; s > 0; s >>= 1) {
        if (tid < s) {
            sE[tid] += sE[tid + s];
            sM[tid] = fmaxf(sM[tid], sM[tid + s]);
            sA[tid] |= sA[tid + s];
        }
        __syncthreads();
    }
    const float scale = sA[0] ? fmaxf(sM[0], 3.0590232e-7f /*e^-15*/) : sM[0];
    const float dn = sE[0] + 1e-6f * scale;
    if (tid == 0) denom[b] = dn;
    const float inv = 1.f / dn;
    for (int t = tid; t < TT; t += 256) e[t] *= inv;
}

// ---------------------------------------------------------------------------
// Kernel 4: z[b,d] = (sum_c zpart[b*BPB+c][d]) / denom[b]
// ---------------------------------------------------------------------------
__global__ __launch_bounds__(256) void zfinal_kernel(
    const float* __restrict__ zpart, const float* __restrict__ denom,
    float* __restrict__ out_z) {
    const int idx = blockIdx.x * 256 + threadIdx.x; // 0 .. B*D-1
    const int b = idx >> 7, d = idx & 127;
    const float* __restrict__ zp = zpart + (size_t)b * BPB * DD + d;
    float s = 0.f;
#pragma unroll
    for (int cc = 0; cc < BPB; ++cc) s += zp[cc * DD];
    out_z[idx] = s / denom[b];
}

// ---------------------------------------------------------------------------
extern "C" void kernel_launch(void* const* d_in, const int* in_sizes, int n_in,
                              void* d_out, int out_size, void* d_ws, size_t ws_size,
                              hipStream_t stream) {
    const float* H     = (const float*)d_in[0]; // [B,T,D] f32
    const int*   mask  = (const int*)d_in[1];   // [B,T] int32
    const float* h_tm1 = (const float*)d_in[2]; // [B,D] f32
    const float* V_w   = (const float*)d_in[3]; // [D,D] f32
    const float* V_b   = (const float*)d_in[4]; // [D] f32
    const float* Wa_w  = (const float*)d_in[5]; // [D,D] f32
    const float* Wa_b  = (const float*)d_in[6]; // [D] f32
    const float* v     = (const float*)d_in[7]; // [D] f32
    const float* c     = (const float*)d_in[8]; // [1] f32

    float* out_z    = (float*)d_out;           // B*D f32
    float* out_beta = (float*)d_out + BB * DD; // B*T f32

    float* ws    = (float*)d_ws;
    float* fkp   = ws;                    // B*D        = 8192 f32
    float* zpart = fkp + BB * DD;         // NBLK*DD    = 524288 f32
    float* denom = zpart + NBLK * DD;     // BB         = 64 f32

    fkprime_kernel<<<BB, DD, 0, stream>>>(Wa_w, Wa_b, h_tm1, fkp);
    beta_z_kernel<<<NBLK, 256, 0, stream>>>(H, V_w, V_b, fkp, v, c, mask,
                                            out_beta, zpart);
    denom_kernel<<<BB, 256, 0, stream>>>(out_beta, mask, denom);
    zfinal_kernel<<<(BB * DD) / 256, 256, 0, stream>>>(zpart, denom, out_z);
}

// Round 8
// 118.779 us; speedup vs baseline: 4.8636x; 1.4938x over previous
//
#include <hip/hip_runtime.h>
#include <math.h>

#define BB 64
#define TT 8192
#define DD 128
#define RPB 64                  // rows per block
#define BPB (TT / RPB)          // z-chunks per batch row = 128
#define NBLK (BB * TT / RPB)    // 8192 blocks

typedef float f32x4 __attribute__((ext_vector_type(4)));
typedef __bf16 bf16x8 __attribute__((ext_vector_type(8)));

__device__ __forceinline__ float fast_tanh(float x) {
    float t = __expf(2.f * x);
    return 1.f - 2.f * __builtin_amdgcn_rcpf(t + 1.f);
}

__device__ __forceinline__ bf16x8 cvt8(float4 a, float4 b) {
    bf16x8 r;
    r[0] = (__bf16)a.x; r[1] = (__bf16)a.y; r[2] = (__bf16)a.z; r[3] = (__bf16)a.w;
    r[4] = (__bf16)b.x; r[5] = (__bf16)b.y; r[6] = (__bf16)b.z; r[7] = (__bf16)b.w;
    return r;
}

// ---------------------------------------------------------------------------
// Kernel 0: V_w f32 -> bf16, stored PRE-SWIZZLED in ws: element (r,c) goes to
// r*128 + (c ^ ((r&7)<<3))  (byte-level: ^((r&7)<<4)). Blocks then stage it
// into LDS with a plain linear copy and read B-fragments with the XOR.
// ---------------------------------------------------------------------------
__global__ __launch_bounds__(256) void convw_kernel(const float* __restrict__ Vw,
                                                    __bf16* __restrict__ Vw_bf) {
    const int i = blockIdx.x * 256 + threadIdx.x; // 0 .. 16383
    const int r = i >> 7, cidx = i & 127;
    Vw_bf[r * DD + (cidx ^ ((r & 7) << 3))] = (__bf16)Vw[i];
}

// ---------------------------------------------------------------------------
// Kernel 1: fkp[b,o] = dot(Wa_w[o,:], h_tm1[b,:]) + Wa_b[o]
// ---------------------------------------------------------------------------
__global__ __launch_bounds__(DD) void fkprime_kernel(
    const float* __restrict__ Waw, const float* __restrict__ Wab,
    const float* __restrict__ h_tm1, float* __restrict__ fkp) {
    const int b = blockIdx.x;
    const int o = threadIdx.x;
    const float* __restrict__ w = Waw + o * DD;
    const float* __restrict__ h = h_tm1 + b * DD;
    float a0 = 0.f, a1 = 0.f, a2 = 0.f, a3 = 0.f;
#pragma unroll
    for (int d = 0; d < DD; d += 4) {
        float4 w4 = *reinterpret_cast<const float4*>(w + d);
        a0 = fmaf(w4.x, h[d + 0], a0);
        a1 = fmaf(w4.y, h[d + 1], a1);
        a2 = fmaf(w4.z, h[d + 2], a2);
        a3 = fmaf(w4.w, h[d + 3], a3);
    }
    fkp[b * DD + o] = (a0 + a1) + (a2 + a3) + Wab[o];
}

// ---------------------------------------------------------------------------
// Kernel 2: fused scores + e' + z-partial, everything LDS-resident.
//  - stage: H tile (64 rows, 32 KB f32) coalesced float4 -> ds_write swizzled
//           (byte ^= ((row&7)<<4)); V_w bf16 (32 KB) linear copy (pre-swz).
//  - GEMM:  wave w owns rows [16w,16w+16); A-frags ds_read f32 + cvt,
//           B-frags ds_read bf16x8; 32 MFMA 16x16x32 per thread.
//  - epi:   s = c + sum_o tanh(S+Vb+fkp)*v ; x = clip(s)*m ; e' = exp(x*m-15)*m
//  - z:     zpart[blk][d] = sum_t e'_t * H_lds[t][d]   (no global H re-read)
// ---------------------------------------------------------------------------
__global__ __launch_bounds__(256, 2) void beta_z_kernel(
    const float* __restrict__ H, const __bf16* __restrict__ Vw_bf,
    const float* __restrict__ Vb, const float* __restrict__ fkp,
    const float* __restrict__ vvec, const float* __restrict__ cptr,
    const int* __restrict__ mask,
    float* __restrict__ eout,      // d_out beta region (e' before normalize)
    float* __restrict__ zpart) {   // [NBLK][DD]
    const int tid  = threadIdx.x;
    const int wv   = tid >> 6;
    const int lane = tid & 63;
    const int cl   = lane & 15;
    const int kg   = lane >> 4;
    const int row0 = blockIdx.x * RPB;
    const int b    = row0 >> 13; // T = 8192

    __shared__ float s_h[RPB * DD];   // 32 KB swizzled f32 H tile
    __shared__ short s_vw[DD * DD];   // 32 KB swizzled bf16 V_w
    __shared__ float s_ep[RPB];
    __shared__ float s_z[2][DD];

    // ---- stage (issue all 16 loads, then write) ----
    const float4* __restrict__ Hg = reinterpret_cast<const float4*>(H + (size_t)row0 * DD);
    const uint4*  __restrict__ Wg = reinterpret_cast<const uint4*>(Vw_bf);
    float4 hreg[8];
    uint4  wreg[8];
#pragma unroll
    for (int i = 0; i < 8; ++i) hreg[i] = Hg[i * 256 + tid];
#pragma unroll
    for (int i = 0; i < 8; ++i) wreg[i] = Wg[i * 256 + tid];
#pragma unroll
    for (int i = 0; i < 8; ++i) {
        const int off  = (i * 256 + tid) * 16;   // byte offset in 32 KB tile
        const int trow = off >> 9;               // 512 B per f32 row
        *reinterpret_cast<float4*>((char*)s_h + (off ^ ((trow & 7) << 4))) = hreg[i];
    }
#pragma unroll
    for (int i = 0; i < 8; ++i)
        *reinterpret_cast<uint4*>((char*)s_vw + (i * 256 + tid) * 16) = wreg[i];
    __syncthreads();

    // ---- GEMM: rows 16*wv .. 16*wv+15, all 128 cols ----
    const int ra   = wv * 16 + cl;
    const int swzA = (ra & 7) << 4;
    f32x4 acc[8];
#pragma unroll
    for (int nt = 0; nt < 8; ++nt) acc[nt] = (f32x4){0.f, 0.f, 0.f, 0.f};

#pragma unroll
    for (int kk = 0; kk < 4; ++kk) {
        const int abyte = ra * 512 + kk * 128 + kg * 32;
        float4 a0 = *reinterpret_cast<const float4*>((char*)s_h + ((abyte)      ^ swzA));
        float4 a1 = *reinterpret_cast<const float4*>((char*)s_h + ((abyte + 16) ^ swzA));
        bf16x8 af = cvt8(a0, a1);
#pragma unroll
        for (int nt = 0; nt < 8; ++nt) {
            const int rb    = nt * 16 + cl;
            const int bbyte = (rb * 256 + kk * 64 + kg * 16) ^ ((rb & 7) << 4);
            bf16x8 bfr = *reinterpret_cast<const bf16x8*>((const char*)s_vw + bbyte);
            acc[nt] = __builtin_amdgcn_mfma_f32_16x16x32_bf16(af, bfr, acc[nt], 0, 0, 0);
        }
    }

    // ---- epilogue: tanh, v-weighted row-sum, e' ----
    const float cval = cptr[0];
    float part[4] = {0.f, 0.f, 0.f, 0.f};
#pragma unroll
    for (int nt = 0; nt < 8; ++nt) {
        const int col = nt * 16 + cl;
        const float bias = Vb[col] + fkp[b * DD + col];
        const float vvl  = vvec[col];
#pragma unroll
        for (int j = 0; j < 4; ++j)
            part[j] = fmaf(fast_tanh(acc[nt][j] + bias), vvl, part[j]);
    }
#pragma unroll
    for (int off = 1; off < 16; off <<= 1) {
#pragma unroll
        for (int j = 0; j < 4; ++j) part[j] += __shfl_xor(part[j], off);
    }
    if (cl == 0) {
#pragma unroll
        for (int j = 0; j < 4; ++j) {
            const int lrow = wv * 16 + kg * 4 + j;
            const int g    = row0 + lrow;
            float x  = fminf(fmaxf(cval + part[j], -15.f), 15.f);
            float mv = (float)mask[g];
            float ep = __expf(x * mv - 15.f) * mv;
            eout[g] = ep;
            s_ep[lrow] = ep;
        }
    }
    __syncthreads();

    // ---- z-partial from the LDS H tile ----
    const int d  = tid & 127;
    const int hf = tid >> 7;
    float a = 0.f;
#pragma unroll 8
    for (int t = hf; t < RPB; t += 2) {
        const float hval = *reinterpret_cast<const float*>(
            (char*)s_h + ((t * 512 + d * 4) ^ ((t & 7) << 4)));
        a = fmaf(s_ep[t], hval, a);
    }
    s_z[hf][d] = a;
    __syncthreads();
    if (tid < DD)
        zpart[(size_t)blockIdx.x * DD + tid] = s_z[0][tid] + s_z[1][tid];
}

// ---------------------------------------------------------------------------
// Kernel 3: per-b denom = sum(e') + 1e-6 * e^{gmax-15}; normalize beta in place.
// e^{gmax-15} = any_masked ? max(max e', e^-15) : max e'
// ---------------------------------------------------------------------------
__global__ __launch_bounds__(256) void denom_kernel(
    float* __restrict__ eout, const int* __restrict__ mask,
    float* __restrict__ denom) {
    const int b = blockIdx.x, tid = threadIdx.x;
    float* __restrict__ e = eout + (size_t)b * TT;
    const int* __restrict__ mrow = mask + (size_t)b * TT;
    __shared__ float sE[256], sM[256];
    __shared__ int sA[256];

    float E = 0.f, M = 0.f;
    int any0 = 0;
    for (int t = tid; t < TT; t += 256) {
        float ep = e[t];
        E += ep;
        M = fmaxf(M, ep);
        any0 |= (mrow[t] == 0);
    }
    sE[tid] = E; sM[tid] = M; sA[tid] = any0;
    __syncthreads();
    for (int s = 128; s > 0; s >>= 1) {
        if (tid < s) {
            sE[tid] += sE[tid + s];
            sM[tid] = fmaxf(sM[tid], sM[tid + s]);
            sA[tid] |= sA[tid + s];
        }
        __syncthreads();
    }
    const float scale = sA[0] ? fmaxf(sM[0], 3.0590232e-7f /*e^-15*/) : sM[0];
    const float dn = sE[0] + 1e-6f * scale;
    if (tid == 0) denom[b] = dn;
    const float inv = 1.f / dn;
    for (int t = tid; t < TT; t += 256) e[t] *= inv;
}

// ---------------------------------------------------------------------------
// Kernel 4: z[b,d] = (sum_c zpart[b*BPB+c][d]) / denom[b]
// ---------------------------------------------------------------------------
__global__ __launch_bounds__(256) void zfinal_kernel(
    const float* __restrict__ zpart, const float* __restrict__ denom,
    float* __restrict__ out_z) {
    const int idx = blockIdx.x * 256 + threadIdx.x; // 0 .. B*D-1
    const int b = idx >> 7, d = idx & 127;
    const float* __restrict__ zp = zpart + (size_t)b * BPB * DD + d;
    float s = 0.f;
#pragma unroll 8
    for (int cc = 0; cc < BPB; ++cc) s += zp[cc * DD];
    out_z[idx] = s / denom[b];
}

// ---------------------------------------------------------------------------
extern "C" void kernel_launch(void* const* d_in, const int* in_sizes, int n_in,
                              void* d_out, int out_size, void* d_ws, size_t ws_size,
                              hipStream_t stream) {
    const float* H     = (const float*)d_in[0]; // [B,T,D] f32
    const int*   mask  = (const int*)d_in[1];   // [B,T] int32
    const float* h_tm1 = (const float*)d_in[2]; // [B,D] f32
    const float* V_w   = (const float*)d_in[3]; // [D,D] f32
    const float* V_b   = (const float*)d_in[4]; // [D] f32
    const float* Wa_w  = (const float*)d_in[5]; // [D,D] f32
    const float* Wa_b  = (const float*)d_in[6]; // [D] f32
    const float* v     = (const float*)d_in[7]; // [D] f32
    const float* c     = (const float*)d_in[8]; // [1] f32

    float* out_z    = (float*)d_out;           // B*D f32
    float* out_beta = (float*)d_out + BB * DD; // B*T f32

    float* ws     = (float*)d_ws;
    float* fkp    = ws;                       // B*D       =   8192 f32
    float* zpart  = fkp + BB * DD;            // NBLK*DD   = 1048576 f32
    float* denom  = zpart + NBLK * DD;        // BB        =     64 f32
    __bf16* Vw_bf = (__bf16*)(denom + BB);    // D*D bf16 (pre-swizzled)

    convw_kernel<<<(DD * DD) / 256, 256, 0, stream>>>(V_w, Vw_bf);
    fkprime_kernel<<<BB, DD, 0, stream>>>(Wa_w, Wa_b, h_tm1, fkp);
    beta_z_kernel<<<NBLK, 256, 0, stream>>>(H, Vw_bf, V_b, fkp, v, c, mask,
                                            out_beta, zpart);
    denom_kernel<<<BB, 256, 0, stream>>>(out_beta, mask, denom);
    zfinal_kernel<<<(BB * DD) / 256, 256, 0, stream>>>(zpart, denom, out_z);
}

// Round 10
// 103.680 us; speedup vs baseline: 5.5718x; 1.1456x over previous
//
#include <hip/hip_runtime.h>
#include <math.h>

#define BB 64
#define TT 8192
#define DD 128
#define RPB 64                  // rows per block
#define BPB (TT / RPB)          // z-chunks per batch row = 128
#define NBLK (BB * TT / RPB)    // 8192 blocks

typedef float f32x4 __attribute__((ext_vector_type(4)));
typedef __bf16 bf16x4 __attribute__((ext_vector_type(4)));
typedef __bf16 bf16x8 __attribute__((ext_vector_type(8)));

__device__ __forceinline__ float fast_tanh(float x) {
    float t = __expf(2.f * x);
    return 1.f - 2.f * __builtin_amdgcn_rcpf(t + 1.f);
}

// u = 32-bit word holding two bf16: low 16 bits = element i, high = element i+1
__device__ __forceinline__ float bf_at_lo16(unsigned u) { return __uint_as_float(u << 16); }
__device__ __forceinline__ float bf_at_hi16(unsigned u) { return __uint_as_float(u & 0xffff0000u); }

// ---------------------------------------------------------------------------
// Kernel 0: V_w f32 -> bf16, PRE-SWIZZLED in ws: (r,c) -> r*128 + (c^((r&7)<<3))
// (byte-level ^((r&7)<<4)). Blocks stage it linearly (global_load_lds) and
// apply the XOR on read.
// ---------------------------------------------------------------------------
__global__ __launch_bounds__(256) void convw_kernel(const float* __restrict__ Vw,
                                                    __bf16* __restrict__ Vw_bf) {
    const int i = blockIdx.x * 256 + threadIdx.x; // 0 .. 16383
    const int r = i >> 7, cidx = i & 127;
    Vw_bf[r * DD + (cidx ^ ((r & 7) << 3))] = (__bf16)Vw[i];
}

// ---------------------------------------------------------------------------
// Kernel 1: fkp[b,o] = dot(Wa_w[o,:], h_tm1[b,:]) + Wa_b[o]
// ---------------------------------------------------------------------------
__global__ __launch_bounds__(DD) void fkprime_kernel(
    const float* __restrict__ Waw, const float* __restrict__ Wab,
    const float* __restrict__ h_tm1, float* __restrict__ fkp) {
    const int b = blockIdx.x;
    const int o = threadIdx.x;
    const float* __restrict__ w = Waw + o * DD;
    const float* __restrict__ h = h_tm1 + b * DD;
    float a0 = 0.f, a1 = 0.f, a2 = 0.f, a3 = 0.f;
#pragma unroll
    for (int d = 0; d < DD; d += 4) {
        float4 w4 = *reinterpret_cast<const float4*>(w + d);
        a0 = fmaf(w4.x, h[d + 0], a0);
        a1 = fmaf(w4.y, h[d + 1], a1);
        a2 = fmaf(w4.z, h[d + 2], a2);
        a3 = fmaf(w4.w, h[d + 3], a3);
    }
    fkp[b * DD + o] = (a0 + a1) + (a2 + a3) + Wab[o];
}

// ---------------------------------------------------------------------------
// Kernel 2: fused scores + e' + z-partial. H tile bf16 in LDS (16 KB, swz),
// V_w bf16 in LDS (32 KB, pre-swz via global_load_lds). 3 blocks/CU.
// ---------------------------------------------------------------------------
__global__ __launch_bounds__(256, 3) void beta_z_kernel(
    const float* __restrict__ H, const __bf16* __restrict__ Vw_bf,
    const float* __restrict__ Vb, const float* __restrict__ fkp,
    const float* __restrict__ vvec, const float* __restrict__ cptr,
    const int* __restrict__ mask,
    float* __restrict__ eout,      // d_out beta region (e' before normalize)
    float* __restrict__ zpart) {   // [NBLK][DD]
    const int tid  = threadIdx.x;
    const int wv   = tid >> 6;
    const int lane = tid & 63;
    const int cl   = lane & 15;
    const int kg   = lane >> 4;
    const int row0 = blockIdx.x * RPB;
    const int b    = row0 >> 13; // T = 8192

    __shared__ short s_h[RPB * DD];   // 16 KB swizzled bf16 H tile
    __shared__ short s_vw[DD * DD];   // 32 KB swizzled bf16 V_w
    __shared__ float s_ep[RPB];
    __shared__ float s_z[4][DD];

    // ---- stage V_w: direct global->LDS DMA (ws copy is pre-swizzled).
    // LDS dest is wave-uniform; HW scatters lane i to dest + i*16 (m104).
    {
        const char* __restrict__ wg = (const char*)Vw_bf;
#pragma unroll
        for (int i = 0; i < 8; ++i) {
            __builtin_amdgcn_global_load_lds(
                (const void*)(wg + i * 4096 + wv * 1024 + lane * 16),
                (void*)((char*)s_vw + i * 4096 + wv * 1024), 16, 0, 0);
        }
    }

    // ---- stage H: coalesced f32x4 loads -> cvt bf16 -> swizzled ds_write_b64 ----
    {
        const float4* __restrict__ Hg =
            reinterpret_cast<const float4*>(H + (size_t)row0 * DD);
        float4 hreg[8];
#pragma unroll
        for (int i = 0; i < 8; ++i) hreg[i] = Hg[i * 256 + tid];
#pragma unroll
        for (int i = 0; i < 8; ++i) {
            bf16x4 r;
            r[0] = (__bf16)hreg[i].x; r[1] = (__bf16)hreg[i].y;
            r[2] = (__bf16)hreg[i].z; r[3] = (__bf16)hreg[i].w;
            const int off  = (i * 256 + tid) * 8;  // byte offset in 16 KB bf16 tile
            const int trow = off >> 8;             // 256 B per bf16 row
            *reinterpret_cast<bf16x4*>((char*)s_h + (off ^ ((trow & 7) << 4))) = r;
        }
    }
    __syncthreads();

    // ---- GEMM: wave wv owns rows [16wv,16wv+16), all 128 cols ----
    const int ra   = wv * 16 + cl;
    const int swzA = (ra & 7) << 4;
    f32x4 acc[8];
#pragma unroll
    for (int nt = 0; nt < 8; ++nt) acc[nt] = (f32x4){0.f, 0.f, 0.f, 0.f};

#pragma unroll
    for (int kk = 0; kk < 4; ++kk) {
        const int abyte = ra * 256 + kk * 64 + kg * 16;
        bf16x8 af = *reinterpret_cast<const bf16x8*>((char*)s_h + (abyte ^ swzA));
#pragma unroll
        for (int nt = 0; nt < 8; ++nt) {
            const int rb    = nt * 16 + cl;
            const int bbyte = (rb * 256 + kk * 64 + kg * 16) ^ ((rb & 7) << 4);
            bf16x8 bfr = *reinterpret_cast<const bf16x8*>((const char*)s_vw + bbyte);
            acc[nt] = __builtin_amdgcn_mfma_f32_16x16x32_bf16(af, bfr, acc[nt], 0, 0, 0);
        }
    }

    // ---- epilogue: tanh, v-weighted row-sum, e' ----
    const float cval = cptr[0];
    float part[4] = {0.f, 0.f, 0.f, 0.f};
#pragma unroll
    for (int nt = 0; nt < 8; ++nt) {
        const int col = nt * 16 + cl;
        const float bias = Vb[col] + fkp[b * DD + col];
        const float vvl  = vvec[col];
#pragma unroll
        for (int j = 0; j < 4; ++j)
            part[j] = fmaf(fast_tanh(acc[nt][j] + bias), vvl, part[j]);
    }
#pragma unroll
    for (int off = 1; off < 16; off <<= 1) {
#pragma unroll
        for (int j = 0; j < 4; ++j) part[j] += __shfl_xor(part[j], off);
    }
    if (cl == 0) {
#pragma unroll
        for (int j = 0; j < 4; ++j) {
            const int lrow = wv * 16 + kg * 4 + j;
            const int g    = row0 + lrow;
            float x  = fminf(fmaxf(cval + part[j], -15.f), 15.f);
            float mv = (float)mask[g];
            float ep = __expf(x * mv - 15.f) * mv;
            eout[g] = ep;
            s_ep[lrow] = ep;
        }
    }
    __syncthreads();

    // ---- z-partial from LDS bf16 H tile: each wave owns one t-group ----
    const int dp = tid & 63;   // d-pair index: covers d = 2dp (lo16), 2dp+1 (hi16)
    const int tg = tid >> 6;   // 0..3
    float a0 = 0.f, a1 = 0.f;
    for (int t = tg; t < RPB; t += 4) {
        const unsigned hv = *reinterpret_cast<const unsigned*>(
            (char*)s_h + ((t * 256 + dp * 4) ^ ((t & 7) << 4)));
        const float w = s_ep[t];
        a0 = fmaf(w, bf_at_lo16(hv), a0);  // element 2dp
        a1 = fmaf(w, bf_at_hi16(hv), a1);  // element 2dp+1
    }
    s_z[tg][dp * 2]     = a0;
    s_z[tg][dp * 2 + 1] = a1;
    __syncthreads();
    if (tid < DD) {
        zpart[(size_t)blockIdx.x * DD + tid] =
            (s_z[0][tid] + s_z[1][tid]) + (s_z[2][tid] + s_z[3][tid]);
    }
}

// ---------------------------------------------------------------------------
// Kernel 3: per-b denom = sum(e') + 1e-6 * e^{gmax-15}; normalize beta in place.
// e^{gmax-15} = any_masked ? max(max e', e^-15) : max e'
// ---------------------------------------------------------------------------
__global__ __launch_bounds__(256) void denom_kernel(
    float* __restrict__ eout, const int* __restrict__ mask,
    float* __restrict__ denom) {
    const int b = blockIdx.x, tid = threadIdx.x;
    float* __restrict__ e = eout + (size_t)b * TT;
    const int* __restrict__ mrow = mask + (size_t)b * TT;
    __shared__ float sE[256], sM[256];
    __shared__ int sA[256];

    float E = 0.f, M = 0.f;
    int any0 = 0;
    for (int t = tid; t < TT; t += 256) {
        float ep = e[t];
        E += ep;
        M = fmaxf(M, ep);
        any0 |= (mrow[t] == 0);
    }
    sE[tid] = E; sM[tid] = M; sA[tid] = any0;
    __syncthreads();
    for (int s = 128; s > 0; s >>= 1) {
        if (tid < s) {
            sE[tid] += sE[tid + s];
            sM[tid] = fmaxf(sM[tid], sM[tid + s]);
            sA[tid] |= sA[tid + s];
        }
        __syncthreads();
    }
    const float scale = sA[0] ? fmaxf(sM[0], 3.0590232e-7f /*e^-15*/) : sM[0];
    const float dn = sE[0] + 1e-6f * scale;
    if (tid == 0) denom[b] = dn;
    const float inv = 1.f / dn;
    for (int t = tid; t < TT; t += 256) e[t] *= inv;
}

// ---------------------------------------------------------------------------
// Kernel 4: z[b,d] = (sum_c zpart[b*BPB+c][d]) / denom[b]
// ---------------------------------------------------------------------------
__global__ __launch_bounds__(256) void zfinal_kernel(
    const float* __restrict__ zpart, const float* __restrict__ denom,
    float* __restrict__ out_z) {
    const int idx = blockIdx.x * 256 + threadIdx.x; // 0 .. B*D-1
    const int b = idx >> 7, d = idx & 127;
    const float* __restrict__ zp = zpart + (size_t)b * BPB * DD + d;
    float s = 0.f;
#pragma unroll 8
    for (int cc = 0; cc < BPB; ++cc) s += zp[cc * DD];
    out_z[idx] = s / denom[b];
}

// ---------------------------------------------------------------------------
extern "C" void kernel_launch(void* const* d_in, const int* in_sizes, int n_in,
                              void* d_out, int out_size, void* d_ws, size_t ws_size,
                              hipStream_t stream) {
    const float* H     = (const float*)d_in[0]; // [B,T,D] f32
    const int*   mask  = (const int*)d_in[1];   // [B,T] int32
    const float* h_tm1 = (const float*)d_in[2]; // [B,D] f32
    const float* V_w   = (const float*)d_in[3]; // [D,D] f32
    const float* V_b   = (const float*)d_in[4]; // [D] f32
    const float* Wa_w  = (const float*)d_in[5]; // [D,D] f32
    const float* Wa_b  = (const float*)d_in[6]; // [D] f32
    const float* v     = (const float*)d_in[7]; // [D] f32
    const float* c     = (const float*)d_in[8]; // [1] f32

    float* out_z    = (float*)d_out;           // B*D f32
    float* out_beta = (float*)d_out + BB * DD; // B*T f32

    float* ws     = (float*)d_ws;
    float* fkp    = ws;                       // B*D       =   8192 f32
    float* zpart  = fkp + BB * DD;            // NBLK*DD   = 1048576 f32
    float* denom  = zpart + NBLK * DD;        // BB        =     64 f32
    __bf16* Vw_bf = (__bf16*)(denom + BB);    // D*D bf16 (pre-swizzled)

    convw_kernel<<<(DD * DD) / 256, 256, 0, stream>>>(V_w, Vw_bf);
    fkprime_kernel<<<BB, DD, 0, stream>>>(Wa_w, Wa_b, h_tm1, fkp);
    beta_z_kernel<<<NBLK, 256, 0, stream>>>(H, Vw_bf, V_b, fkp, v, c, mask,
                                            out_beta, zpart);
    denom_kernel<<<BB, 256, 0, stream>>>(out_beta, mask, denom);
    zfinal_kernel<<<(BB * DD) / 256, 256, 0, stream>>>(zpart, denom, out_z);
}

// Round 11
// 94.698 us; speedup vs baseline: 6.1003x; 1.0949x over previous
//
#include <hip/hip_runtime.h>
#include <math.h>

#define BB 64
#define TT 8192
#define DD 128
#define RPT 64                   // rows per tile
#define NT 8                     // tiles per block
#define RPBLK (RPT * NT)         // 512 rows per block
#define NBLK (BB * TT / RPBLK)   // 1024 blocks
#define BPB (TT / RPBLK)         // 16 blocks per batch row

typedef float f32x4 __attribute__((ext_vector_type(4)));
typedef __bf16 bf16x4 __attribute__((ext_vector_type(4)));
typedef __bf16 bf16x8 __attribute__((ext_vector_type(8)));

__device__ __forceinline__ float fast_tanh(float x) {
    float t = __expf(2.f * x);
    return 1.f - 2.f * __builtin_amdgcn_rcpf(t + 1.f);
}

// u = 32-bit word holding two bf16: low 16 bits = element i, high = element i+1
__device__ __forceinline__ float bf_at_lo16(unsigned u) { return __uint_as_float(u << 16); }
__device__ __forceinline__ float bf_at_hi16(unsigned u) { return __uint_as_float(u & 0xffff0000u); }

// ---------------------------------------------------------------------------
// Kernel 0: V_w f32 -> bf16, PRE-SWIZZLED in ws: (r,c) -> r*128 + (c^((r&7)<<3))
// (byte-level ^((r&7)<<4)). Blocks stage it linearly (global_load_lds) and
// apply the XOR on read.
// ---------------------------------------------------------------------------
__global__ __launch_bounds__(256) void convw_kernel(const float* __restrict__ Vw,
                                                    __bf16* __restrict__ Vw_bf) {
    const int i = blockIdx.x * 256 + threadIdx.x; // 0 .. 16383
    const int r = i >> 7, cidx = i & 127;
    Vw_bf[r * DD + (cidx ^ ((r & 7) << 3))] = (__bf16)Vw[i];
}

// ---------------------------------------------------------------------------
// Kernel 1: fkp[b,o] = dot(Wa_w[o,:], h_tm1[b,:]) + Wa_b[o]
// ---------------------------------------------------------------------------
__global__ __launch_bounds__(DD) void fkprime_kernel(
    const float* __restrict__ Waw, const float* __restrict__ Wab,
    const float* __restrict__ h_tm1, float* __restrict__ fkp) {
    const int b = blockIdx.x;
    const int o = threadIdx.x;
    const float* __restrict__ w = Waw + o * DD;
    const float* __restrict__ h = h_tm1 + b * DD;
    float a0 = 0.f, a1 = 0.f, a2 = 0.f, a3 = 0.f;
#pragma unroll
    for (int d = 0; d < DD; d += 4) {
        float4 w4 = *reinterpret_cast<const float4*>(w + d);
        a0 = fmaf(w4.x, h[d + 0], a0);
        a1 = fmaf(w4.y, h[d + 1], a1);
        a2 = fmaf(w4.z, h[d + 2], a2);
        a3 = fmaf(w4.w, h[d + 3], a3);
    }
    fkp[b * DD + o] = (a0 + a1) + (a2 + a3) + Wab[o];
}

// ---------------------------------------------------------------------------
// Kernel 2: fused scores + e' + z-partial; 8 tiles/block, double-buffered.
// Per iteration: issue next loads -> GEMM+epi -> bar -> z -> write buf -> bar.
// ---------------------------------------------------------------------------
__global__ __launch_bounds__(256, 2) void beta_z_kernel(
    const float* __restrict__ H, const __bf16* __restrict__ Vw_bf,
    const float* __restrict__ Vb, const float* __restrict__ fkp,
    const float* __restrict__ vvec, const float* __restrict__ cptr,
    const int* __restrict__ mask,
    float* __restrict__ eout,      // d_out beta region (e' before normalize)
    float* __restrict__ zpart) {   // [NBLK][DD]
    const int tid  = threadIdx.x;
    const int wv   = tid >> 6;
    const int lane = tid & 63;
    const int cl   = lane & 15;
    const int kg   = lane >> 4;
    const int base_row = blockIdx.x * RPBLK;
    const int b    = base_row >> 13; // T = 8192; 512 | 8192 so block is one b

    __shared__ short s_vw[DD * DD];      // 32 KB swizzled bf16 V_w
    __shared__ short s_h[2][RPT * DD];   // 2 x 16 KB swizzled bf16 H tiles
    __shared__ float s_ep[RPT];
    __shared__ float s_z[4][DD];

    // ---- prologue: V_w via global_load_lds (ws copy pre-swizzled) ----
    {
        const char* __restrict__ wg = (const char*)Vw_bf;
#pragma unroll
        for (int i = 0; i < 8; ++i) {
            __builtin_amdgcn_global_load_lds(
                (const void*)(wg + i * 4096 + wv * 1024 + lane * 16),
                (void*)((char*)s_vw + i * 4096 + wv * 1024), 16, 0, 0);
        }
    }
    // tile 0 H loads -> cvt -> swizzled write to buf 0
    float4 hreg[8];
    {
        const float4* __restrict__ Hg =
            reinterpret_cast<const float4*>(H + (size_t)base_row * DD);
#pragma unroll
        for (int i = 0; i < 8; ++i) hreg[i] = Hg[i * 256 + tid];
#pragma unroll
        for (int i = 0; i < 8; ++i) {
            bf16x4 r;
            r[0] = (__bf16)hreg[i].x; r[1] = (__bf16)hreg[i].y;
            r[2] = (__bf16)hreg[i].z; r[3] = (__bf16)hreg[i].w;
            const int off  = (i * 256 + tid) * 8;  // byte offset in 16 KB tile
            const int trow = off >> 8;             // 256 B per bf16 row
            *reinterpret_cast<bf16x4*>((char*)s_h[0] + (off ^ ((trow & 7) << 4))) = r;
        }
    }
    __syncthreads();  // drains vmcnt (V_w DMA) + lgkm; buf0 + s_vw ready

    const float cval = cptr[0];
    const int   ra   = wv * 16 + cl;
    const int   swzA = (ra & 7) << 4;
    const int   dp   = tid & 63;   // d-pair: d = 2dp (lo16), 2dp+1 (hi16)
    const int   tg   = tid >> 6;
    float za0 = 0.f, za1 = 0.f;    // z accumulators across all 8 tiles

    for (int t = 0; t < NT; ++t) {
        const int cur = t & 1;

        // ---- issue next tile's loads (hidden under this tile's compute) ----
        if (t + 1 < NT) {
            const float4* __restrict__ Hn = reinterpret_cast<const float4*>(
                H + (size_t)(base_row + (t + 1) * RPT) * DD);
#pragma unroll
            for (int i = 0; i < 8; ++i) hreg[i] = Hn[i * 256 + tid];
        }

        // ---- GEMM: wave wv owns rows [16wv,16wv+16) of this tile ----
        f32x4 acc[8];
#pragma unroll
        for (int nt = 0; nt < 8; ++nt) acc[nt] = (f32x4){0.f, 0.f, 0.f, 0.f};
#pragma unroll
        for (int kk = 0; kk < 4; ++kk) {
            const int abyte = ra * 256 + kk * 64 + kg * 16;
            bf16x8 af = *reinterpret_cast<const bf16x8*>(
                (char*)s_h[cur] + (abyte ^ swzA));
#pragma unroll
            for (int nt = 0; nt < 8; ++nt) {
                const int rb    = nt * 16 + cl;
                const int bbyte = (rb * 256 + kk * 64 + kg * 16) ^ ((rb & 7) << 4);
                bf16x8 bfr = *reinterpret_cast<const bf16x8*>((const char*)s_vw + bbyte);
                acc[nt] = __builtin_amdgcn_mfma_f32_16x16x32_bf16(af, bfr, acc[nt], 0, 0, 0);
            }
        }

        // ---- epilogue: tanh, v-weighted row-sum, e' ----
        float part[4] = {0.f, 0.f, 0.f, 0.f};
#pragma unroll
        for (int nt = 0; nt < 8; ++nt) {
            const int col = nt * 16 + cl;
            const float bias = Vb[col] + fkp[b * DD + col];
            const float vvl  = vvec[col];
#pragma unroll
            for (int j = 0; j < 4; ++j)
                part[j] = fmaf(fast_tanh(acc[nt][j] + bias), vvl, part[j]);
        }
#pragma unroll
        for (int off = 1; off < 16; off <<= 1) {
#pragma unroll
            for (int j = 0; j < 4; ++j) part[j] += __shfl_xor(part[j], off);
        }
        if (cl == 0) {
#pragma unroll
            for (int j = 0; j < 4; ++j) {
                const int lrow = wv * 16 + kg * 4 + j;
                const int g    = base_row + t * RPT + lrow;
                float x  = fminf(fmaxf(cval + part[j], -15.f), 15.f);
                float mv = (float)mask[g];
                float ep = __expf(x * mv - 15.f) * mv;
                eout[g] = ep;
                s_ep[lrow] = ep;
            }
        }
        __syncthreads();  // barrier 1: s_ep visible; GEMM reads of buf done

        // ---- z-accumulate (registers, across tiles) ----
        for (int tt = tg; tt < RPT; tt += 4) {
            const unsigned hv = *reinterpret_cast<const unsigned*>(
                (char*)s_h[cur] + ((tt * 256 + dp * 4) ^ ((tt & 7) << 4)));
            const float w = s_ep[tt];
            za0 = fmaf(w, bf_at_lo16(hv), za0);  // element 2dp
            za1 = fmaf(w, bf_at_hi16(hv), za1);  // element 2dp+1
        }

        // ---- write next tile into the other buffer (vmcnt waits inserted) ----
        if (t + 1 < NT) {
#pragma unroll
            for (int i = 0; i < 8; ++i) {
                bf16x4 r;
                r[0] = (__bf16)hreg[i].x; r[1] = (__bf16)hreg[i].y;
                r[2] = (__bf16)hreg[i].z; r[3] = (__bf16)hreg[i].w;
                const int off  = (i * 256 + tid) * 8;
                const int trow = off >> 8;
                *reinterpret_cast<bf16x4*>(
                    (char*)s_h[cur ^ 1] + (off ^ ((trow & 7) << 4))) = r;
            }
        }
        __syncthreads();  // barrier 2: next buf ready for all waves
    }

    // ---- final z-partial write (one per block) ----
    s_z[tg][dp * 2]     = za0;
    s_z[tg][dp * 2 + 1] = za1;
    __syncthreads();
    if (tid < DD) {
        zpart[(size_t)blockIdx.x * DD + tid] =
            (s_z[0][tid] + s_z[1][tid]) + (s_z[2][tid] + s_z[3][tid]);
    }
}

// ---------------------------------------------------------------------------
// Kernel 3: per-b denom = sum(e') + 1e-6 * e^{gmax-15}; normalize beta in place.
// e^{gmax-15} = any_masked ? max(max e', e^-15) : max e'
// ---------------------------------------------------------------------------
__global__ __launch_bounds__(256) void denom_kernel(
    float* __restrict__ eout, const int* __restrict__ mask,
    float* __restrict__ denom) {
    const int b = blockIdx.x, tid = threadIdx.x;
    float* __restrict__ e = eout + (size_t)b * TT;
    const int* __restrict__ mrow = mask + (size_t)b * TT;
    __shared__ float sE[256], sM[256];
    __shared__ int sA[256];

    float E = 0.f, M = 0.f;
    int any0 = 0;
    for (int t = tid; t < TT; t += 256) {
        float ep = e[t];
        E += ep;
        M = fmaxf(M, ep);
        any0 |= (mrow[t] == 0);
    }
    sE[tid] = E; sM[tid] = M; sA[tid] = any0;
    __syncthreads();
    for (int s = 128; s > 0; s >>= 1) {
        if (tid < s) {
            sE[tid] += sE[tid + s];
            sM[tid] = fmaxf(sM[tid], sM[tid + s]);
            sA[tid] |= sA[tid + s];
        }
        __syncthreads();
    }
    const float scale = sA[0] ? fmaxf(sM[0], 3.0590232e-7f /*e^-15*/) : sM[0];
    const float dn = sE[0] + 1e-6f * scale;
    if (tid == 0) denom[b] = dn;
    const float inv = 1.f / dn;
    for (int t = tid; t < TT; t += 256) e[t] *= inv;
}

// ---------------------------------------------------------------------------
// Kernel 4: z[b,d] = (sum_c zpart[b*BPB+c][d]) / denom[b]
// ---------------------------------------------------------------------------
__global__ __launch_bounds__(256) void zfinal_kernel(
    const float* __restrict__ zpart, const float* __restrict__ denom,
    float* __restrict__ out_z) {
    const int idx = blockIdx.x * 256 + threadIdx.x; // 0 .. B*D-1
    const int b = idx >> 7, d = idx & 127;
    const float* __restrict__ zp = zpart + (size_t)b * BPB * DD + d;
    float s = 0.f;
#pragma unroll
    for (int cc = 0; cc < BPB; ++cc) s += zp[cc * DD];
    out_z[idx] = s / denom[b];
}

// ---------------------------------------------------------------------------
extern "C" void kernel_launch(void* const* d_in, const int* in_sizes, int n_in,
                              void* d_out, int out_size, void* d_ws, size_t ws_size,
                              hipStream_t stream) {
    const float* H     = (const float*)d_in[0]; // [B,T,D] f32
    const int*   mask  = (const int*)d_in[1];   // [B,T] int32
    const float* h_tm1 = (const float*)d_in[2]; // [B,D] f32
    const float* V_w   = (const float*)d_in[3]; // [D,D] f32
    const float* V_b   = (const float*)d_in[4]; // [D] f32
    const float* Wa_w  = (const float*)d_in[5]; // [D,D] f32
    const float* Wa_b  = (const float*)d_in[6]; // [D] f32
    const float* v     = (const float*)d_in[7]; // [D] f32
    const float* c     = (const float*)d_in[8]; // [1] f32

    float* out_z    = (float*)d_out;           // B*D f32
    float* out_beta = (float*)d_out + BB * DD; // B*T f32

    float* ws     = (float*)d_ws;
    float* fkp    = ws;                       // B*D     =   8192 f32
    float* zpart  = fkp + BB * DD;            // NBLK*DD = 131072 f32
    float* denom  = zpart + NBLK * DD;        // BB      =     64 f32
    __bf16* Vw_bf = (__bf16*)(denom + BB);    // D*D bf16 (pre-swizzled)

    convw_kernel<<<(DD * DD) / 256, 256, 0, stream>>>(V_w, Vw_bf);
    fkprime_kernel<<<BB, DD, 0, stream>>>(Wa_w, Wa_b, h_tm1, fkp);
    beta_z_kernel<<<NBLK, 256, 0, stream>>>(H, Vw_bf, V_b, fkp, v, c, mask,
                                            out_beta, zpart);
    denom_kernel<<<BB, 256, 0, stream>>>(out_beta, mask, denom);
    zfinal_kernel<<<(BB * DD) / 256, 256, 0, stream>>>(zpart, denom, out_z);
}